// Round 4
// baseline (658.991 us; speedup 1.0000x reference)
//
#include <hip/hip_runtime.h>
#include <stdint.h>

#define RS32 0.17677669529663687f  // 1/sqrt(32)
#define LDW 40                     // ushort stride per LDS row (32 + 8 pad; 80B, 16B-aligned)

typedef short bf16x8 __attribute__((ext_vector_type(8)));
typedef float f32x4 __attribute__((ext_vector_type(4)));

__device__ __forceinline__ ushort f2bf(float f) {
  uint32_t b = __float_as_uint(f);
  b = (b + 0x7fffu + ((b >> 16) & 1u)) >> 16;
  return (ushort)b;
}
__device__ __forceinline__ float bflo(uint32_t w) { return __uint_as_float(w << 16); }
__device__ __forceinline__ float bfhi(uint32_t w) { return __uint_as_float(w & 0xffff0000u); }

// split 16 fp32 into hi/lo bf16 and store to LDS row r at koff (both 16B-aligned stores)
__device__ __forceinline__ void stage16(ushort* hiA, ushort* loA, int r, int koff,
                                        const float* v) {
  uint32_t hu[8], lu[8];
#pragma unroll
  for (int i = 0; i < 8; ++i) {
    ushort h0 = f2bf(v[2 * i]), h1 = f2bf(v[2 * i + 1]);
    float f0 = __uint_as_float(((uint32_t)h0) << 16);
    float f1 = __uint_as_float(((uint32_t)h1) << 16);
    ushort l0 = f2bf(v[2 * i] - f0), l1 = f2bf(v[2 * i + 1] - f1);
    hu[i] = (uint32_t)h0 | ((uint32_t)h1 << 16);
    lu[i] = (uint32_t)l0 | ((uint32_t)l1 << 16);
  }
  *(uint4*)&hiA[r * LDW + koff]     = make_uint4(hu[0], hu[1], hu[2], hu[3]);
  *(uint4*)&hiA[r * LDW + koff + 8] = make_uint4(hu[4], hu[5], hu[6], hu[7]);
  *(uint4*)&loA[r * LDW + koff]     = make_uint4(lu[0], lu[1], lu[2], lu[3]);
  *(uint4*)&loA[r * LDW + koff + 8] = make_uint4(lu[4], lu[5], lu[6], lu[7]);
}

// ---------------- MFMA bf16x3 GEMM: out = ep(g(A) @ W^T), N x 128, K=128 ----------------
// mode 1: g=relu(A+A2), ep=+bias.  mode 2: g=relu((A-mu)*inv), ep=+bias+X.
// block: 256 thr = 4 waves in 2x2; wave owns 64x64; mfma_f32_16x16x32_bf16.
__launch_bounds__(256)
__global__ void gemm128_mfma_kernel(int mode,
                                    const float* __restrict__ A, const float* __restrict__ A2,
                                    const float* __restrict__ W, const float* __restrict__ bias,
                                    const float* __restrict__ mu, const float* __restrict__ inv,
                                    const float* __restrict__ X, float* __restrict__ out, int N)
{
  __shared__ ushort Ahi[128 * LDW], Alo[128 * LDW], Whi[128 * LDW], Wlo[128 * LDW];
  const int tid = threadIdx.x;
  const int nb = blockIdx.x * 128;
  const int lane = tid & 63, wv = tid >> 6;
  const int wr = (wv >> 1) * 64, wc = (wv & 1) * 64;
  const int fr = lane & 15, fq = lane >> 4;
  const int sr = tid >> 1, sk = (tid & 1) * 16;

  f32x4 acc[4][4];
#pragma unroll
  for (int m = 0; m < 4; ++m)
#pragma unroll
    for (int n = 0; n < 4; ++n) acc[m][n] = (f32x4)0.0f;

  for (int kc = 0; kc < 128; kc += 32) {
    float va[16], vw[16];
    {
      int gr = nb + sr;
      if (gr < N) {
#pragma unroll
        for (int i = 0; i < 4; ++i) {
          float4 v = *(const float4*)(A + (size_t)gr * 128 + kc + sk + i * 4);
          if (mode == 1) {
            float4 b = *(const float4*)(A2 + (size_t)gr * 128 + kc + sk + i * 4);
            v.x = fmaxf(v.x + b.x, 0.f); v.y = fmaxf(v.y + b.y, 0.f);
            v.z = fmaxf(v.z + b.z, 0.f); v.w = fmaxf(v.w + b.w, 0.f);
          } else if (mode == 2) {
            float4 m4 = *(const float4*)(mu + kc + sk + i * 4);
            float4 i4 = *(const float4*)(inv + kc + sk + i * 4);
            v.x = fmaxf((v.x - m4.x) * i4.x, 0.f); v.y = fmaxf((v.y - m4.y) * i4.y, 0.f);
            v.z = fmaxf((v.z - m4.z) * i4.z, 0.f); v.w = fmaxf((v.w - m4.w) * i4.w, 0.f);
          }
          va[i * 4 + 0] = v.x; va[i * 4 + 1] = v.y; va[i * 4 + 2] = v.z; va[i * 4 + 3] = v.w;
        }
      } else {
#pragma unroll
        for (int i = 0; i < 16; ++i) va[i] = 0.f;
      }
#pragma unroll
      for (int i = 0; i < 4; ++i) {
        float4 v = *(const float4*)(W + (size_t)sr * 128 + kc + sk + i * 4);
        vw[i * 4 + 0] = v.x; vw[i * 4 + 1] = v.y; vw[i * 4 + 2] = v.z; vw[i * 4 + 3] = v.w;
      }
    }
    if (kc) __syncthreads();
    stage16(Ahi, Alo, sr, sk, va);
    stage16(Whi, Wlo, sr, sk, vw);
    __syncthreads();

    bf16x8 ah[4], al[4], bh[4], bl[4];
#pragma unroll
    for (int m = 0; m < 4; ++m) {
      const int row = wr + m * 16 + fr;
      ah[m] = *(const bf16x8*)&Ahi[row * LDW + fq * 8];
      al[m] = *(const bf16x8*)&Alo[row * LDW + fq * 8];
    }
#pragma unroll
    for (int n = 0; n < 4; ++n) {
      const int col = wc + n * 16 + fr;
      bh[n] = *(const bf16x8*)&Whi[col * LDW + fq * 8];
      bl[n] = *(const bf16x8*)&Wlo[col * LDW + fq * 8];
    }
#pragma unroll
    for (int m = 0; m < 4; ++m)
#pragma unroll
      for (int n = 0; n < 4; ++n) {
        acc[m][n] = __builtin_amdgcn_mfma_f32_16x16x32_bf16(ah[m], bh[n], acc[m][n], 0, 0, 0);
        acc[m][n] = __builtin_amdgcn_mfma_f32_16x16x32_bf16(al[m], bh[n], acc[m][n], 0, 0, 0);
        acc[m][n] = __builtin_amdgcn_mfma_f32_16x16x32_bf16(ah[m], bl[n], acc[m][n], 0, 0, 0);
      }
  }

  float bcol[4];
#pragma unroll
  for (int n = 0; n < 4; ++n) bcol[n] = bias[wc + n * 16 + fr];
#pragma unroll
  for (int m = 0; m < 4; ++m) {
    const int r0 = nb + wr + m * 16 + fq * 4;
#pragma unroll
    for (int r = 0; r < 4; ++r) {
      const int gr = r0 + r;
      if (gr < N) {
#pragma unroll
        for (int n = 0; n < 4; ++n) {
          const int c = wc + n * 16 + fr;
          float o = acc[m][n][r] + bcol[n];
          if (mode == 2) o += X[(size_t)gr * 128 + c];
          out[(size_t)gr * 128 + c] = o;
        }
      }
    }
  }
}

// ---------------- MFMA QKVS: 4 weight sets selected by blockIdx.y, no input transform ----
__launch_bounds__(256)
__global__ void gemmqkvs_mfma_kernel(const float* __restrict__ x,
                                     const float* __restrict__ Wq, const float* __restrict__ bq,
                                     const float* __restrict__ Wk, const float* __restrict__ bk,
                                     const float* __restrict__ Wv, const float* __restrict__ bv,
                                     const float* __restrict__ Ws, const float* __restrict__ bs,
                                     float* __restrict__ oq, float* __restrict__ ok,
                                     float* __restrict__ ov, float* __restrict__ os, int N)
{
  const float* W; const float* bias; float* out;
  if (blockIdx.y == 0)      { W = Wq; bias = bq; out = oq; }
  else if (blockIdx.y == 1) { W = Wk; bias = bk; out = ok; }
  else if (blockIdx.y == 2) { W = Wv; bias = bv; out = ov; }
  else                      { W = Ws; bias = bs; out = os; }

  __shared__ ushort Ahi[128 * LDW], Alo[128 * LDW], Whi[128 * LDW], Wlo[128 * LDW];
  const int tid = threadIdx.x;
  const int nb = blockIdx.x * 128;
  const int lane = tid & 63, wv = tid >> 6;
  const int wr = (wv >> 1) * 64, wc = (wv & 1) * 64;
  const int fr = lane & 15, fq = lane >> 4;
  const int sr = tid >> 1, sk = (tid & 1) * 16;

  f32x4 acc[4][4];
#pragma unroll
  for (int m = 0; m < 4; ++m)
#pragma unroll
    for (int n = 0; n < 4; ++n) acc[m][n] = (f32x4)0.0f;

  for (int kc = 0; kc < 128; kc += 32) {
    float va[16], vw[16];
    {
      int gr = nb + sr;
      if (gr < N) {
#pragma unroll
        for (int i = 0; i < 4; ++i) {
          float4 v = *(const float4*)(x + (size_t)gr * 128 + kc + sk + i * 4);
          va[i * 4 + 0] = v.x; va[i * 4 + 1] = v.y; va[i * 4 + 2] = v.z; va[i * 4 + 3] = v.w;
        }
      } else {
#pragma unroll
        for (int i = 0; i < 16; ++i) va[i] = 0.f;
      }
#pragma unroll
      for (int i = 0; i < 4; ++i) {
        float4 v = *(const float4*)(W + (size_t)sr * 128 + kc + sk + i * 4);
        vw[i * 4 + 0] = v.x; vw[i * 4 + 1] = v.y; vw[i * 4 + 2] = v.z; vw[i * 4 + 3] = v.w;
      }
    }
    if (kc) __syncthreads();
    stage16(Ahi, Alo, sr, sk, va);
    stage16(Whi, Wlo, sr, sk, vw);
    __syncthreads();

    bf16x8 ah[4], al[4], bh[4], bl[4];
#pragma unroll
    for (int m = 0; m < 4; ++m) {
      const int row = wr + m * 16 + fr;
      ah[m] = *(const bf16x8*)&Ahi[row * LDW + fq * 8];
      al[m] = *(const bf16x8*)&Alo[row * LDW + fq * 8];
    }
#pragma unroll
    for (int n = 0; n < 4; ++n) {
      const int col = wc + n * 16 + fr;
      bh[n] = *(const bf16x8*)&Whi[col * LDW + fq * 8];
      bl[n] = *(const bf16x8*)&Wlo[col * LDW + fq * 8];
    }
#pragma unroll
    for (int m = 0; m < 4; ++m)
#pragma unroll
      for (int n = 0; n < 4; ++n) {
        acc[m][n] = __builtin_amdgcn_mfma_f32_16x16x32_bf16(ah[m], bh[n], acc[m][n], 0, 0, 0);
        acc[m][n] = __builtin_amdgcn_mfma_f32_16x16x32_bf16(al[m], bh[n], acc[m][n], 0, 0, 0);
        acc[m][n] = __builtin_amdgcn_mfma_f32_16x16x32_bf16(ah[m], bl[n], acc[m][n], 0, 0, 0);
      }
  }

  float bcol[4];
#pragma unroll
  for (int n = 0; n < 4; ++n) bcol[n] = bias[wc + n * 16 + fr];
#pragma unroll
  for (int m = 0; m < 4; ++m) {
    const int r0 = nb + wr + m * 16 + fq * 4;
#pragma unroll
    for (int r = 0; r < 4; ++r) {
      const int gr = r0 + r;
      if (gr < N) {
#pragma unroll
        for (int n = 0; n < 4; ++n) {
          const int c = wc + n * 16 + fr;
          out[(size_t)gr * 128 + c] = acc[m][n][r] + bcol[n];
        }
      }
    }
  }
}

// ---------------- u[n, h*128+j] = sum_{c<32} q[n, 32h+c] * We[32h+c, j]  (bf16 out) ----------------
__launch_bounds__(256)
__global__ void u_kernel(const float* __restrict__ q, const float* __restrict__ We,
                         ushort* __restrict__ u, int N)
{
  __shared__ float qs[64][128];
  const int tid = threadIdx.x;
  const int nb = blockIdx.x * 64;
  for (int idx = tid; idx < 64 * 128; idx += 256) {
    int r = idx >> 7, kk = idx & 127;
    qs[r][kk] = (nb + r < N) ? q[(size_t)(nb + r) * 128 + kk] : 0.f;
  }
  __syncthreads();
  const int j = tid & 127, half = tid >> 7;
  for (int h = 0; h < 4; ++h) {
    float w[32];
#pragma unroll
    for (int c = 0; c < 32; ++c) w[c] = We[(size_t)(32 * h + c) * 128 + j];
    for (int nn = half; nn < 64; nn += 2) {
      float acc = 0.f;
#pragma unroll
      for (int c4 = 0; c4 < 32; c4 += 4) {
        float4 qq = *(const float4*)&qs[nn][32 * h + c4];
        acc = fmaf(qq.x, w[c4], acc);
        acc = fmaf(qq.y, w[c4 + 1], acc);
        acc = fmaf(qq.z, w[c4 + 2], acc);
        acc = fmaf(qq.w, w[c4 + 3], acc);
      }
      int gr = nb + nn;
      if (gr < N) u[(size_t)gr * 512 + h * 128 + j] = f2bf(acc);
    }
  }
}

// ---------------- pack We as bf16 channel-pairs: WePg[l*128+kk] = bf16(We[2l,kk]) | bf16(We[2l+1,kk])<<16
__global__ void prep_we_kernel(const float* __restrict__ We, uint32_t* __restrict__ WePg)
{
  int idx = blockIdx.x * 256 + threadIdx.x;   // 64*128 entries
  if (idx >= 64 * 128) return;
  int l = idx >> 7, kk = idx & 127;
  uint32_t lo = f2bf(We[(size_t)(2 * l) * 128 + kk]);
  uint32_t hi = f2bf(We[(size_t)(2 * l + 1) * 128 + kk]);
  WePg[idx] = lo | (hi << 16);
}

// ---------------- CSR build (no ordered scan: ranges assigned by atomic) ----------------
__global__ void deg_kernel(const int* __restrict__ ei, int* __restrict__ deg, int E)
{
  int e = blockIdx.x * 256 + threadIdx.x;
  if (e < E) atomicAdd(&deg[ei[E + e]], 1);
}

__launch_bounds__(256)
__global__ void start_kernel(const int* __restrict__ deg, int* __restrict__ offs,
                             int* __restrict__ cursor, int* __restrict__ gcount, int N)
{
  const int i = blockIdx.x * 256 + threadIdx.x;
  const int lane = threadIdx.x & 63;
  int d = (i < N) ? deg[i] : 0;
  int scan = d;
#pragma unroll
  for (int ofs = 1; ofs < 64; ofs <<= 1) {
    int t = __shfl_up(scan, ofs, 64);
    if (lane >= ofs) scan += t;
  }
  int total = __shfl(scan, 63, 64);
  int base = 0;
  if (lane == 63) base = atomicAdd(gcount, total);
  base = __shfl(base, 63, 64);
  int excl = base + scan - d;
  if (i < N) { offs[i] = excl; cursor[i] = excl; }
}

__global__ void fill_kernel(const int* __restrict__ ei, int* __restrict__ cursor,
                            int2* __restrict__ csr, int E)
{
  int e = blockIdx.x * 256 + threadIdx.x;
  if (e < E) {
    int dst = ei[E + e];
    int slot = atomicAdd(&cursor[dst], 1);
    csr[slot] = make_int2(ei[e], e);
  }
}

// ---------------- fused node-major attention: score + softmax + aggregate + We tail ----------------
// wave per node; 4 edge-subgroups of 16 lanes; lane (g,m): channels 8m..8m+7 (head m>>2).
// tail: lane owns channels {2*lane, 2*lane+1} (head lane>>4); We read from global (L1/L2).
__launch_bounds__(256)
__global__ void fused_attn_kernel(const int2* __restrict__ csr, const int* __restrict__ offs,
                                  const int* __restrict__ deg,
                                  const float* __restrict__ q, const float* __restrict__ kbuf,
                                  const float* __restrict__ vbuf, const ushort* __restrict__ u,
                                  const float* __restrict__ eattr,
                                  const uint32_t* __restrict__ WePg,
                                  float* __restrict__ attn, int N)
{
  __shared__ __align__(16) float aggP[4][4 * 132 + 128];   // per wave: agg[4][132] + ws[128]
  const int tid = threadIdx.x;
  const int lane = tid & 63;
  const int wid = tid >> 6;
  const int g = lane >> 4;        // edge subgroup 0..3
  const int m = lane & 15;
  const int c0 = m * 8;
  const int h = m >> 2;           // head of my 8 channels
  const int hp = lane >> 4;       // tail: head of channels {2*lane, 2*lane+1}
  float* aggW = aggP[wid];
  float* wsW = aggP[wid] + 4 * 132;

  const int gwave = blockIdx.x * 4 + wid;
  const int nwaves = gridDim.x * 4;

  for (int n = gwave; n < N; n += nwaves) {
    const int e0 = offs[n];
    const int e1 = e0 + deg[n];

    const float4 qA = *(const float4*)(q + (size_t)n * 128 + c0);
    const float4 qB = *(const float4*)(q + (size_t)n * 128 + c0 + 4);
    float uh[4][8];
#pragma unroll
    for (int hh = 0; hh < 4; ++hh) {
      const uint4 U = *(const uint4*)(u + (size_t)n * 512 + hh * 128 + c0);
      uh[hh][0] = bflo(U.x); uh[hh][1] = bfhi(U.x);
      uh[hh][2] = bflo(U.y); uh[hh][3] = bfhi(U.y);
      uh[hh][4] = bflo(U.z); uh[hh][5] = bfhi(U.z);
      uh[hh][6] = bflo(U.w); uh[hh][7] = bfhi(U.w);
    }

    float ws[8], ax[4][8], sums4[4];
#pragma unroll
    for (int j = 0; j < 8; ++j) ws[j] = 0.f;
#pragma unroll
    for (int hh = 0; hh < 4; ++hh) {
      sums4[hh] = 0.f;
#pragma unroll
      for (int j = 0; j < 8; ++j) ax[hh][j] = 0.f;
    }

    for (int sl = e0 + g; sl < e1; sl += 4) {
      const int2 se = csr[sl];
      const float* ea = eattr + (size_t)se.y * 128 + c0;
      const float* kp = kbuf + (size_t)se.x * 128 + c0;
      const float* vp = vbuf + (size_t)se.x * 128 + c0;
      const float4 eaA = *(const float4*)ea;
      const float4 eaB = *(const float4*)(ea + 4);
      const float4 kA = *(const float4*)kp;
      const float4 kB = *(const float4*)(kp + 4);
      const float4 vA = *(const float4*)vp;
      const float4 vB = *(const float4*)(vp + 4);
      const float eaf[8] = {eaA.x, eaA.y, eaA.z, eaA.w, eaB.x, eaB.y, eaB.z, eaB.w};
      const float vf[8]  = {vA.x, vA.y, vA.z, vA.w, vB.x, vB.y, vB.z, vB.w};

      float P[4];
#pragma unroll
      for (int hh = 0; hh < 4; ++hh) {
        float s = 0.f;
#pragma unroll
        for (int j = 0; j < 8; ++j) s = fmaf(eaf[j], uh[hh][j], s);
        P[hh] = s;
      }
      float qk = qA.x * kA.x + qA.y * kA.y + qA.z * kA.z + qA.w * kA.w
               + qB.x * kB.x + qB.y * kB.y + qB.z * kB.z + qB.w * kB.w;
      P[0] += (h == 0) ? qk : 0.f;
      P[1] += (h == 1) ? qk : 0.f;
      P[2] += (h == 2) ? qk : 0.f;
      P[3] += (h == 3) ? qk : 0.f;

#pragma unroll
      for (int mm = 1; mm <= 8; mm <<= 1) {
        P[0] += __shfl_xor(P[0], mm, 64);
        P[1] += __shfl_xor(P[1], mm, 64);
        P[2] += __shfl_xor(P[2], mm, 64);
        P[3] += __shfl_xor(P[3], mm, 64);
      }
      float a4[4];
#pragma unroll
      for (int hh = 0; hh < 4; ++hh) {
        a4[hh] = __expf(P[hh] * RS32);
        sums4[hh] += a4[hh];
      }
      const float aV = (h == 0) ? a4[0] : (h == 1) ? a4[1] : (h == 2) ? a4[2] : a4[3];
#pragma unroll
      for (int j = 0; j < 8; ++j) ws[j] = fmaf(aV, vf[j], ws[j]);
#pragma unroll
      for (int hh = 0; hh < 4; ++hh)
#pragma unroll
        for (int j = 0; j < 8; ++j) ax[hh][j] = fmaf(a4[hh], eaf[j], ax[hh][j]);
    }

    // combine across the 4 edge-subgroups
#pragma unroll
    for (int mm = 16; mm <= 32; mm <<= 1) {
#pragma unroll
      for (int j = 0; j < 8; ++j) ws[j] += __shfl_xor(ws[j], mm, 64);
#pragma unroll
      for (int hh = 0; hh < 4; ++hh) {
        sums4[hh] += __shfl_xor(sums4[hh], mm, 64);
#pragma unroll
        for (int j = 0; j < 8; ++j) ax[hh][j] += __shfl_xor(ax[hh][j], mm, 64);
      }
    }

    float axg[8];
#pragma unroll
    for (int j = 0; j < 8; ++j)
      axg[j] = (g == 0) ? ax[0][j] : (g == 1) ? ax[1][j] : (g == 2) ? ax[2][j] : ax[3][j];
#pragma unroll
    for (int j = 0; j < 8; ++j) aggW[g * 132 + c0 + j] = axg[j];
    if (g == 0) {
#pragma unroll
      for (int j = 0; j < 8; ++j) wsW[c0 + j] = ws[j];
    }

    // We tail: d[c] = sum_k We[c,k] * agg[h(c)][k], c = {2*lane, 2*lane+1}; We rows from global
    float d0 = 0.f, d1 = 0.f;
    const float* agp = &aggW[hp * 132];
    const uint32_t* wrow = WePg + (size_t)lane * 128;
#pragma unroll 4
    for (int kk = 0; kk < 128; kk += 4) {
      const uint4 w4 = *(const uint4*)&wrow[kk];
      const float4 a4v = *(const float4*)&agp[kk];
      d0 = fmaf(bflo(w4.x), a4v.x, d0); d1 = fmaf(bfhi(w4.x), a4v.x, d1);
      d0 = fmaf(bflo(w4.y), a4v.y, d0); d1 = fmaf(bfhi(w4.y), a4v.y, d1);
      d0 = fmaf(bflo(w4.z), a4v.z, d0); d1 = fmaf(bfhi(w4.z), a4v.z, d1);
      d0 = fmaf(bflo(w4.w), a4v.w, d0); d1 = fmaf(bfhi(w4.w), a4v.w, d1);
    }
    const float s = (hp == 0) ? sums4[0] : (hp == 1) ? sums4[1] : (hp == 2) ? sums4[2] : sums4[3];
    const float iv = (s > 0.f) ? 1.f / s : 0.f;
    const float2 wsp = *(const float2*)&wsW[2 * lane];
    *(float2*)(attn + (size_t)n * 128 + 2 * lane) =
        make_float2((wsp.x + d0) * iv, (wsp.y + d1) * iv);
  }
}

// ---------------- column LayerNorm stats over node dim ----------------
__launch_bounds__(256)
__global__ void stats_kernel(const float* __restrict__ t1, float* __restrict__ sums,
                             float* __restrict__ sumsq, int N)
{
  const int tid = threadIdx.x;
  const int c = tid & 127, half = tid >> 7;
  float s = 0.f, s2 = 0.f;
  for (int r = blockIdx.x * 2 + half; r < N; r += gridDim.x * 2) {
    float vv = t1[(size_t)r * 128 + c];
    s += vv; s2 = fmaf(vv, vv, s2);
  }
  __shared__ float ls[256], ls2[256];
  ls[tid] = s; ls2[tid] = s2;
  __syncthreads();
  if (tid < 128) {
    atomicAdd(&sums[c], ls[tid] + ls[tid + 128]);
    atomicAdd(&sumsq[c], ls2[tid] + ls2[tid + 128]);
  }
}

__global__ void finalize_stats_kernel(const float* __restrict__ sums, const float* __restrict__ sumsq,
                                      float* __restrict__ mu, float* __restrict__ inv, int N)
{
  int c = threadIdx.x;
  float m = sums[c] / (float)N;
  float var = sumsq[c] / (float)N - m * m;
  float sd = sqrtf(fmaxf(var, 0.f));
  mu[c] = m;
  inv[c] = 1.f / (sd + 1e-5f);
}

extern "C" void kernel_launch(void* const* d_in, const int* in_sizes, int n_in,
                              void* d_out, int out_size, void* d_ws, size_t ws_size,
                              hipStream_t stream) {
  const float* x    = (const float*)d_in[0];
  const int*   ei   = (const int*)d_in[1];
  const float* eatt = (const float*)d_in[2];
  const float* Wq = (const float*)d_in[3];  const float* bq = (const float*)d_in[4];
  const float* Wk = (const float*)d_in[5];  const float* bk = (const float*)d_in[6];
  const float* Wv = (const float*)d_in[7];  const float* bv = (const float*)d_in[8];
  const float* We = (const float*)d_in[9];
  const float* Wsk = (const float*)d_in[10]; const float* bsk = (const float*)d_in[11];
  const float* Wp = (const float*)d_in[12]; const float* bp = (const float*)d_in[13];
  const float* Wm = (const float*)d_in[14]; const float* bm = (const float*)d_in[15];
  float* out = (float*)d_out;

  const int N = in_sizes[0] / 128;
  const int E = in_sizes[1] / 2;

  char* w = (char*)d_ws;
  auto alloc = [&](size_t bytes) {
    char* p = w;
    w += (bytes + 255) & ~(size_t)255;
    return p;
  };
  const size_t node_f = (size_t)N * 128 * sizeof(float);
  float*  q    = (float*)alloc(node_f);
  float*  kk   = (float*)alloc(node_f);
  float*  vv   = (float*)alloc(node_f);
  float*  skip = (float*)alloc(node_f);
  float*  attn = (float*)alloc(node_f);
  ushort* u    = (ushort*)alloc((size_t)N * 512 * sizeof(ushort));
  uint32_t* WePg = (uint32_t*)alloc(64 * 128 * sizeof(uint32_t));
  int*    deg  = (int*)alloc((size_t)N * sizeof(int));
  int*    offs = (int*)alloc((size_t)N * sizeof(int));
  int*    curs = (int*)alloc((size_t)N * sizeof(int));
  int*    gcnt = (int*)alloc(sizeof(int));
  int2*   csr  = (int2*)alloc((size_t)E * sizeof(int2));
  float*  sums  = (float*)alloc(128 * sizeof(float));
  float*  sumsq = (float*)alloc(128 * sizeof(float));
  float*  mu    = (float*)alloc(128 * sizeof(float));
  float*  inv   = (float*)alloc(128 * sizeof(float));
  float*  t1   = q;   // q dead after fused_attn; reuse
  (void)ws_size; (void)n_in; (void)out_size;

  const int NB = (N + 127) / 128;
  const int EB = (E + 255) / 256;

  hipMemsetAsync(deg, 0, (size_t)N * sizeof(int), stream);
  hipMemsetAsync(gcnt, 0, sizeof(int), stream);
  hipMemsetAsync(sums, 0, 2 * 128 * sizeof(float), stream);  // sums + sumsq contiguous

  // node projections: q,k,v,skip in one launch (MFMA bf16x3)
  gemmqkvs_mfma_kernel<<<dim3(NB, 4), 256, 0, stream>>>(x, Wq, bq, Wk, bk, Wv, bv, Wsk, bsk,
                                                        q, kk, vv, skip, N);
  u_kernel<<<(N + 63) / 64, 256, 0, stream>>>(q, We, u, N);
  prep_we_kernel<<<32, 256, 0, stream>>>(We, WePg);

  // CSR by dst (ranges in arbitrary order)
  deg_kernel<<<EB, 256, 0, stream>>>(ei, deg, E);
  start_kernel<<<(N + 255) / 256, 256, 0, stream>>>(deg, offs, curs, gcnt, N);
  fill_kernel<<<EB, 256, 0, stream>>>(ei, curs, csr, E);

  // fused attention: scores + softmax + aggregation + We tail
  fused_attn_kernel<<<2048, 256, 0, stream>>>(csr, offs, deg, q, kk, vv, u, eatt, WePg, attn, N);

  // t1 = relu(attn + skip) @ Wp^T + bp  (MFMA bf16x3)
  gemm128_mfma_kernel<<<NB, 256, 0, stream>>>(1, attn, skip, Wp, bp, nullptr, nullptr, nullptr, t1, N);

  // column LayerNorm over node dim
  stats_kernel<<<256, 256, 0, stream>>>(t1, sums, sumsq, N);
  finalize_stats_kernel<<<1, 128, 0, stream>>>(sums, sumsq, mu, inv, N);

  // out = relu((t1 - mu) * inv) @ Wm^T + bm + x  (MFMA bf16x3)
  gemm128_mfma_kernel<<<NB, 256, 0, stream>>>(2, t1, nullptr, Wm, bm, mu, inv, x, out, N);
}

// Round 5
// 559.141 us; speedup vs baseline: 1.1786x; 1.1786x over previous
//
#include <hip/hip_runtime.h>
#include <stdint.h>

#define RS32 0.17677669529663687f  // 1/sqrt(32)
#define LDW 40                     // ushort stride per LDS row (32 + 8 pad; 80B, 16B-aligned)

typedef short bf16x8 __attribute__((ext_vector_type(8)));
typedef float f32x4 __attribute__((ext_vector_type(4)));

__device__ __forceinline__ ushort f2bf(float f) {
  uint32_t b = __float_as_uint(f);
  b = (b + 0x7fffu + ((b >> 16) & 1u)) >> 16;
  return (ushort)b;
}
__device__ __forceinline__ float bflo(uint32_t w) { return __uint_as_float(w << 16); }
__device__ __forceinline__ float bfhi(uint32_t w) { return __uint_as_float(w & 0xffff0000u); }

// split 16 fp32 into hi/lo bf16 and store to LDS row r at koff (both 16B-aligned stores)
__device__ __forceinline__ void stage16(ushort* hiA, ushort* loA, int r, int koff,
                                        const float* v) {
  uint32_t hu[8], lu[8];
#pragma unroll
  for (int i = 0; i < 8; ++i) {
    ushort h0 = f2bf(v[2 * i]), h1 = f2bf(v[2 * i + 1]);
    float f0 = __uint_as_float(((uint32_t)h0) << 16);
    float f1 = __uint_as_float(((uint32_t)h1) << 16);
    ushort l0 = f2bf(v[2 * i] - f0), l1 = f2bf(v[2 * i + 1] - f1);
    hu[i] = (uint32_t)h0 | ((uint32_t)h1 << 16);
    lu[i] = (uint32_t)l0 | ((uint32_t)l1 << 16);
  }
  *(uint4*)&hiA[r * LDW + koff]     = make_uint4(hu[0], hu[1], hu[2], hu[3]);
  *(uint4*)&hiA[r * LDW + koff + 8] = make_uint4(hu[4], hu[5], hu[6], hu[7]);
  *(uint4*)&loA[r * LDW + koff]     = make_uint4(lu[0], lu[1], lu[2], lu[3]);
  *(uint4*)&loA[r * LDW + koff + 8] = make_uint4(lu[4], lu[5], lu[6], lu[7]);
}

// ---------------- MFMA bf16x3 GEMM: out = ep(g(A) @ W^T), N x 128, K=128 ----------------
// mode 1: g=relu(A+A2), ep=+bias.  mode 2: g=relu((A-mu)*inv), ep=+bias+X.
__launch_bounds__(256)
__global__ void gemm128_mfma_kernel(int mode,
                                    const float* __restrict__ A, const float* __restrict__ A2,
                                    const float* __restrict__ W, const float* __restrict__ bias,
                                    const float* __restrict__ mu, const float* __restrict__ inv,
                                    const float* __restrict__ X, float* __restrict__ out, int N)
{
  __shared__ ushort Ahi[128 * LDW], Alo[128 * LDW], Whi[128 * LDW], Wlo[128 * LDW];
  const int tid = threadIdx.x;
  const int nb = blockIdx.x * 128;
  const int lane = tid & 63, wv = tid >> 6;
  const int wr = (wv >> 1) * 64, wc = (wv & 1) * 64;
  const int fr = lane & 15, fq = lane >> 4;
  const int sr = tid >> 1, sk = (tid & 1) * 16;

  f32x4 acc[4][4];
#pragma unroll
  for (int m = 0; m < 4; ++m)
#pragma unroll
    for (int n = 0; n < 4; ++n) acc[m][n] = (f32x4)0.0f;

  for (int kc = 0; kc < 128; kc += 32) {
    float va[16], vw[16];
    {
      int gr = nb + sr;
      if (gr < N) {
#pragma unroll
        for (int i = 0; i < 4; ++i) {
          float4 v = *(const float4*)(A + (size_t)gr * 128 + kc + sk + i * 4);
          if (mode == 1) {
            float4 b = *(const float4*)(A2 + (size_t)gr * 128 + kc + sk + i * 4);
            v.x = fmaxf(v.x + b.x, 0.f); v.y = fmaxf(v.y + b.y, 0.f);
            v.z = fmaxf(v.z + b.z, 0.f); v.w = fmaxf(v.w + b.w, 0.f);
          } else if (mode == 2) {
            float4 m4 = *(const float4*)(mu + kc + sk + i * 4);
            float4 i4 = *(const float4*)(inv + kc + sk + i * 4);
            v.x = fmaxf((v.x - m4.x) * i4.x, 0.f); v.y = fmaxf((v.y - m4.y) * i4.y, 0.f);
            v.z = fmaxf((v.z - m4.z) * i4.z, 0.f); v.w = fmaxf((v.w - m4.w) * i4.w, 0.f);
          }
          va[i * 4 + 0] = v.x; va[i * 4 + 1] = v.y; va[i * 4 + 2] = v.z; va[i * 4 + 3] = v.w;
        }
      } else {
#pragma unroll
        for (int i = 0; i < 16; ++i) va[i] = 0.f;
      }
#pragma unroll
      for (int i = 0; i < 4; ++i) {
        float4 v = *(const float4*)(W + (size_t)sr * 128 + kc + sk + i * 4);
        vw[i * 4 + 0] = v.x; vw[i * 4 + 1] = v.y; vw[i * 4 + 2] = v.z; vw[i * 4 + 3] = v.w;
      }
    }
    if (kc) __syncthreads();
    stage16(Ahi, Alo, sr, sk, va);
    stage16(Whi, Wlo, sr, sk, vw);
    __syncthreads();

    bf16x8 ah[4], al[4], bh[4], bl[4];
#pragma unroll
    for (int m = 0; m < 4; ++m) {
      const int row = wr + m * 16 + fr;
      ah[m] = *(const bf16x8*)&Ahi[row * LDW + fq * 8];
      al[m] = *(const bf16x8*)&Alo[row * LDW + fq * 8];
    }
#pragma unroll
    for (int n = 0; n < 4; ++n) {
      const int col = wc + n * 16 + fr;
      bh[n] = *(const bf16x8*)&Whi[col * LDW + fq * 8];
      bl[n] = *(const bf16x8*)&Wlo[col * LDW + fq * 8];
    }
#pragma unroll
    for (int m = 0; m < 4; ++m)
#pragma unroll
      for (int n = 0; n < 4; ++n) {
        acc[m][n] = __builtin_amdgcn_mfma_f32_16x16x32_bf16(ah[m], bh[n], acc[m][n], 0, 0, 0);
        acc[m][n] = __builtin_amdgcn_mfma_f32_16x16x32_bf16(al[m], bh[n], acc[m][n], 0, 0, 0);
        acc[m][n] = __builtin_amdgcn_mfma_f32_16x16x32_bf16(ah[m], bl[n], acc[m][n], 0, 0, 0);
      }
  }

  float bcol[4];
#pragma unroll
  for (int n = 0; n < 4; ++n) bcol[n] = bias[wc + n * 16 + fr];
#pragma unroll
  for (int m = 0; m < 4; ++m) {
    const int r0 = nb + wr + m * 16 + fq * 4;
#pragma unroll
    for (int r = 0; r < 4; ++r) {
      const int gr = r0 + r;
      if (gr < N) {
#pragma unroll
        for (int n = 0; n < 4; ++n) {
          const int c = wc + n * 16 + fr;
          float o = acc[m][n][r] + bcol[n];
          if (mode == 2) o += X[(size_t)gr * 128 + c];
          out[(size_t)gr * 128 + c] = o;
        }
      }
    }
  }
}

// ---------------- MFMA QKVS: 4 weight sets selected by blockIdx.y ----------------
__launch_bounds__(256)
__global__ void gemmqkvs_mfma_kernel(const float* __restrict__ x,
                                     const float* __restrict__ Wq, const float* __restrict__ bq,
                                     const float* __restrict__ Wk, const float* __restrict__ bk,
                                     const float* __restrict__ Wv, const float* __restrict__ bv,
                                     const float* __restrict__ Ws, const float* __restrict__ bs,
                                     float* __restrict__ oq, float* __restrict__ ok,
                                     float* __restrict__ ov, float* __restrict__ os, int N)
{
  const float* W; const float* bias; float* out;
  if (blockIdx.y == 0)      { W = Wq; bias = bq; out = oq; }
  else if (blockIdx.y == 1) { W = Wk; bias = bk; out = ok; }
  else if (blockIdx.y == 2) { W = Wv; bias = bv; out = ov; }
  else                      { W = Ws; bias = bs; out = os; }

  __shared__ ushort Ahi[128 * LDW], Alo[128 * LDW], Whi[128 * LDW], Wlo[128 * LDW];
  const int tid = threadIdx.x;
  const int nb = blockIdx.x * 128;
  const int lane = tid & 63, wv = tid >> 6;
  const int wr = (wv >> 1) * 64, wc = (wv & 1) * 64;
  const int fr = lane & 15, fq = lane >> 4;
  const int sr = tid >> 1, sk = (tid & 1) * 16;

  f32x4 acc[4][4];
#pragma unroll
  for (int m = 0; m < 4; ++m)
#pragma unroll
    for (int n = 0; n < 4; ++n) acc[m][n] = (f32x4)0.0f;

  for (int kc = 0; kc < 128; kc += 32) {
    float va[16], vw[16];
    {
      int gr = nb + sr;
      if (gr < N) {
#pragma unroll
        for (int i = 0; i < 4; ++i) {
          float4 v = *(const float4*)(x + (size_t)gr * 128 + kc + sk + i * 4);
          va[i * 4 + 0] = v.x; va[i * 4 + 1] = v.y; va[i * 4 + 2] = v.z; va[i * 4 + 3] = v.w;
        }
      } else {
#pragma unroll
        for (int i = 0; i < 16; ++i) va[i] = 0.f;
      }
#pragma unroll
      for (int i = 0; i < 4; ++i) {
        float4 v = *(const float4*)(W + (size_t)sr * 128 + kc + sk + i * 4);
        vw[i * 4 + 0] = v.x; vw[i * 4 + 1] = v.y; vw[i * 4 + 2] = v.z; vw[i * 4 + 3] = v.w;
      }
    }
    if (kc) __syncthreads();
    stage16(Ahi, Alo, sr, sk, va);
    stage16(Whi, Wlo, sr, sk, vw);
    __syncthreads();

    bf16x8 ah[4], al[4], bh[4], bl[4];
#pragma unroll
    for (int m = 0; m < 4; ++m) {
      const int row = wr + m * 16 + fr;
      ah[m] = *(const bf16x8*)&Ahi[row * LDW + fq * 8];
      al[m] = *(const bf16x8*)&Alo[row * LDW + fq * 8];
    }
#pragma unroll
    for (int n = 0; n < 4; ++n) {
      const int col = wc + n * 16 + fr;
      bh[n] = *(const bf16x8*)&Whi[col * LDW + fq * 8];
      bl[n] = *(const bf16x8*)&Wlo[col * LDW + fq * 8];
    }
#pragma unroll
    for (int m = 0; m < 4; ++m)
#pragma unroll
      for (int n = 0; n < 4; ++n) {
        acc[m][n] = __builtin_amdgcn_mfma_f32_16x16x32_bf16(ah[m], bh[n], acc[m][n], 0, 0, 0);
        acc[m][n] = __builtin_amdgcn_mfma_f32_16x16x32_bf16(al[m], bh[n], acc[m][n], 0, 0, 0);
        acc[m][n] = __builtin_amdgcn_mfma_f32_16x16x32_bf16(ah[m], bl[n], acc[m][n], 0, 0, 0);
      }
  }

  float bcol[4];
#pragma unroll
  for (int n = 0; n < 4; ++n) bcol[n] = bias[wc + n * 16 + fr];
#pragma unroll
  for (int m = 0; m < 4; ++m) {
    const int r0 = nb + wr + m * 16 + fq * 4;
#pragma unroll
    for (int r = 0; r < 4; ++r) {
      const int gr = r0 + r;
      if (gr < N) {
#pragma unroll
        for (int n = 0; n < 4; ++n) {
          const int c = wc + n * 16 + fr;
          out[(size_t)gr * 128 + c] = acc[m][n][r] + bcol[n];
        }
      }
    }
  }
}

// ---------------- u[n, h*128+j] = sum_{c<32} q[n, 32h+c] * We[32h+c, j]  (bf16 out) ----------------
__launch_bounds__(256)
__global__ void u_kernel(const float* __restrict__ q, const float* __restrict__ We,
                         ushort* __restrict__ u, int N)
{
  __shared__ float qs[64][128];
  const int tid = threadIdx.x;
  const int nb = blockIdx.x * 64;
  for (int idx = tid; idx < 64 * 128; idx += 256) {
    int r = idx >> 7, kk = idx & 127;
    qs[r][kk] = (nb + r < N) ? q[(size_t)(nb + r) * 128 + kk] : 0.f;
  }
  __syncthreads();
  const int j = tid & 127, half = tid >> 7;
  for (int h = 0; h < 4; ++h) {
    float w[32];
#pragma unroll
    for (int c = 0; c < 32; ++c) w[c] = We[(size_t)(32 * h + c) * 128 + j];
    for (int nn = half; nn < 64; nn += 2) {
      float acc = 0.f;
#pragma unroll
      for (int c4 = 0; c4 < 32; c4 += 4) {
        float4 qq = *(const float4*)&qs[nn][32 * h + c4];
        acc = fmaf(qq.x, w[c4], acc);
        acc = fmaf(qq.y, w[c4 + 1], acc);
        acc = fmaf(qq.z, w[c4 + 2], acc);
        acc = fmaf(qq.w, w[c4 + 3], acc);
      }
      int gr = nb + nn;
      if (gr < N) u[(size_t)gr * 512 + h * 128 + j] = f2bf(acc);
    }
  }
}

// ---------------- WeB[c][h*128+k] = (h == c>>5) ? bf16(We[c,k]) : 0  (block-diag, 128x512) ----
__global__ void prep_web_kernel(const float* __restrict__ We, ushort* __restrict__ WeB)
{
  int idx = blockIdx.x * 256 + threadIdx.x;
  if (idx >= 128 * 512) return;
  int c = idx >> 9, j = idx & 511;
  int hh = j >> 7, k2 = j & 127;
  WeB[idx] = (hh == (c >> 5)) ? f2bf(We[(size_t)c * 128 + k2]) : (ushort)0;
}

// ---------------- CSR build ----------------
__global__ void deg_kernel(const int* __restrict__ ei, int* __restrict__ deg, int E)
{
  int e = blockIdx.x * 256 + threadIdx.x;
  if (e < E) atomicAdd(&deg[ei[E + e]], 1);
}

__launch_bounds__(256)
__global__ void start_kernel(const int* __restrict__ deg, int* __restrict__ offs,
                             int* __restrict__ cursor, int* __restrict__ gcount, int N)
{
  const int i = blockIdx.x * 256 + threadIdx.x;
  const int lane = threadIdx.x & 63;
  int d = (i < N) ? deg[i] : 0;
  int scan = d;
#pragma unroll
  for (int ofs = 1; ofs < 64; ofs <<= 1) {
    int t = __shfl_up(scan, ofs, 64);
    if (lane >= ofs) scan += t;
  }
  int total = __shfl(scan, 63, 64);
  int base = 0;
  if (lane == 63) base = atomicAdd(gcount, total);
  base = __shfl(base, 63, 64);
  int excl = base + scan - d;
  if (i < N) { offs[i] = excl; cursor[i] = excl; }
}

__global__ void fill_kernel(const int* __restrict__ ei, int* __restrict__ cursor,
                            int2* __restrict__ csr, int E)
{
  int e = blockIdx.x * 256 + threadIdx.x;
  if (e < E) {
    int dst = ei[E + e];
    int slot = atomicAdd(&cursor[dst], 1);
    csr[slot] = make_int2(ei[e], e);
  }
}

// ---------------- fused node-major attention: score + softmax + aggregate ----------------
// wave per node; 2 edge slots of 32 lanes; lane (p, j32) owns channels 4*j32..+3 (head j32>>3).
// Outputs: aggS[n][h*128+k] = (sum_e a*ea)[h][k]*iv_h (bf16), wsS[n][c] = (sum a*v)[c]*iv_h(c).
// We-contraction deferred to agg_gemm_kernel (MFMA).
__launch_bounds__(256)
__global__ void fused_attn2_kernel(const int2* __restrict__ csr, const int* __restrict__ offs,
                                   const int* __restrict__ deg,
                                   const float* __restrict__ q, const float* __restrict__ kbuf,
                                   const float* __restrict__ vbuf, const ushort* __restrict__ u,
                                   const float* __restrict__ eattr,
                                   ushort* __restrict__ aggS, float* __restrict__ wsS, int N)
{
  const int tid = threadIdx.x;
  const int lane = tid & 63;
  const int wid = tid >> 6;
  const int p = lane >> 5;          // edge slot 0/1
  const int j32 = lane & 31;
  const int c0 = j32 * 4;           // my 4 channels
  const int h = j32 >> 3;           // head of my channels
  const int gwave = blockIdx.x * 4 + wid;
  const int nwaves = gridDim.x * 4;

  for (int n = gwave; n < N; n += nwaves) {
    const int e0 = offs[n];
    const int e1 = e0 + deg[n];

    const float4 qv = *(const float4*)(q + (size_t)n * 128 + c0);
    float uh[4][4];
#pragma unroll
    for (int hh = 0; hh < 4; ++hh) {
      uint2 U = *(const uint2*)(u + (size_t)n * 512 + hh * 128 + c0);
      uh[hh][0] = bflo(U.x); uh[hh][1] = bfhi(U.x);
      uh[hh][2] = bflo(U.y); uh[hh][3] = bfhi(U.y);
    }

    float ws0 = 0.f, ws1 = 0.f, ws2 = 0.f, ws3 = 0.f;
    float ax[4][4];
#pragma unroll
    for (int hh = 0; hh < 4; ++hh)
#pragma unroll
      for (int j = 0; j < 4; ++j) ax[hh][j] = 0.f;
    float sm0 = 0.f, sm1 = 0.f, sm2 = 0.f, sm3 = 0.f;

    int sl = e0 + p;
    if (sl < e1) {
      int2 seC = csr[sl];
      float4 eaC = *(const float4*)(eattr + (size_t)seC.y * 128 + c0);
      float4 kC  = *(const float4*)(kbuf + (size_t)seC.x * 128 + c0);
      float4 vC  = *(const float4*)(vbuf + (size_t)seC.x * 128 + c0);
      int sln = sl + 2;
      int2 seN = (sln < e1) ? csr[sln] : seC;
      for (; sl < e1; sl += 2) {
        // prefetch next edge's rows + csr two ahead
        float4 eaN = *(const float4*)(eattr + (size_t)seN.y * 128 + c0);
        float4 kN  = *(const float4*)(kbuf + (size_t)seN.x * 128 + c0);
        float4 vN  = *(const float4*)(vbuf + (size_t)seN.x * 128 + c0);
        const int slf = sl + 4;
        int2 seF = (slf < e1) ? csr[slf] : seN;

        // scores for current edge
        float P0 = eaC.x * uh[0][0] + eaC.y * uh[0][1] + eaC.z * uh[0][2] + eaC.w * uh[0][3];
        float P1 = eaC.x * uh[1][0] + eaC.y * uh[1][1] + eaC.z * uh[1][2] + eaC.w * uh[1][3];
        float P2 = eaC.x * uh[2][0] + eaC.y * uh[2][1] + eaC.z * uh[2][2] + eaC.w * uh[2][3];
        float P3 = eaC.x * uh[3][0] + eaC.y * uh[3][1] + eaC.z * uh[3][2] + eaC.w * uh[3][3];
        const float qk = qv.x * kC.x + qv.y * kC.y + qv.z * kC.z + qv.w * kC.w;
        P0 += (h == 0) ? qk : 0.f;
        P1 += (h == 1) ? qk : 0.f;
        P2 += (h == 2) ? qk : 0.f;
        P3 += (h == 3) ? qk : 0.f;
#pragma unroll
        for (int mm = 1; mm <= 16; mm <<= 1) {
          P0 += __shfl_xor(P0, mm, 64);
          P1 += __shfl_xor(P1, mm, 64);
          P2 += __shfl_xor(P2, mm, 64);
          P3 += __shfl_xor(P3, mm, 64);
        }
        const float a0 = __expf(P0 * RS32);
        const float a1 = __expf(P1 * RS32);
        const float a2 = __expf(P2 * RS32);
        const float a3 = __expf(P3 * RS32);
        sm0 += a0; sm1 += a1; sm2 += a2; sm3 += a3;
        const float aV = (h == 0) ? a0 : (h == 1) ? a1 : (h == 2) ? a2 : a3;
        ws0 = fmaf(aV, vC.x, ws0); ws1 = fmaf(aV, vC.y, ws1);
        ws2 = fmaf(aV, vC.z, ws2); ws3 = fmaf(aV, vC.w, ws3);
        ax[0][0] = fmaf(a0, eaC.x, ax[0][0]); ax[0][1] = fmaf(a0, eaC.y, ax[0][1]);
        ax[0][2] = fmaf(a0, eaC.z, ax[0][2]); ax[0][3] = fmaf(a0, eaC.w, ax[0][3]);
        ax[1][0] = fmaf(a1, eaC.x, ax[1][0]); ax[1][1] = fmaf(a1, eaC.y, ax[1][1]);
        ax[1][2] = fmaf(a1, eaC.z, ax[1][2]); ax[1][3] = fmaf(a1, eaC.w, ax[1][3]);
        ax[2][0] = fmaf(a2, eaC.x, ax[2][0]); ax[2][1] = fmaf(a2, eaC.y, ax[2][1]);
        ax[2][2] = fmaf(a2, eaC.z, ax[2][2]); ax[2][3] = fmaf(a2, eaC.w, ax[2][3]);
        ax[3][0] = fmaf(a3, eaC.x, ax[3][0]); ax[3][1] = fmaf(a3, eaC.y, ax[3][1]);
        ax[3][2] = fmaf(a3, eaC.z, ax[3][2]); ax[3][3] = fmaf(a3, eaC.w, ax[3][3]);

        eaC = eaN; kC = kN; vC = vN; seN = seF;
      }
    }

    // combine the two edge slots (xor 32)
#pragma unroll
    for (int hh = 0; hh < 4; ++hh)
#pragma unroll
      for (int j = 0; j < 4; ++j) ax[hh][j] += __shfl_xor(ax[hh][j], 32, 64);
    ws0 += __shfl_xor(ws0, 32, 64); ws1 += __shfl_xor(ws1, 32, 64);
    ws2 += __shfl_xor(ws2, 32, 64); ws3 += __shfl_xor(ws3, 32, 64);
    sm0 += __shfl_xor(sm0, 32, 64); sm1 += __shfl_xor(sm1, 32, 64);
    sm2 += __shfl_xor(sm2, 32, 64); sm3 += __shfl_xor(sm3, 32, 64);

    const float iv0 = (sm0 > 0.f) ? 1.f / sm0 : 0.f;
    const float iv1 = (sm1 > 0.f) ? 1.f / sm1 : 0.f;
    const float iv2 = (sm2 > 0.f) ? 1.f / sm2 : 0.f;
    const float iv3 = (sm3 > 0.f) ? 1.f / sm3 : 0.f;

    if (p == 0) {
      const float s = (h == 0) ? iv0 : (h == 1) ? iv1 : (h == 2) ? iv2 : iv3;
      *(float4*)(wsS + (size_t)n * 128 + c0) =
          make_float4(ws0 * s, ws1 * s, ws2 * s, ws3 * s);
    }

    // lane writes heads {2p, 2p+1} for its channel quad
    float o0[4], o1[4], s0, s1;
    if (p == 0) {
#pragma unroll
      for (int j = 0; j < 4; ++j) { o0[j] = ax[0][j]; o1[j] = ax[1][j]; }
      s0 = iv0; s1 = iv1;
    } else {
#pragma unroll
      for (int j = 0; j < 4; ++j) { o0[j] = ax[2][j]; o1[j] = ax[3][j]; }
      s0 = iv2; s1 = iv3;
    }
    uint2 w0 = make_uint2(((uint32_t)f2bf(o0[0] * s0)) | (((uint32_t)f2bf(o0[1] * s0)) << 16),
                          ((uint32_t)f2bf(o0[2] * s0)) | (((uint32_t)f2bf(o0[3] * s0)) << 16));
    uint2 w1 = make_uint2(((uint32_t)f2bf(o1[0] * s1)) | (((uint32_t)f2bf(o1[1] * s1)) << 16),
                          ((uint32_t)f2bf(o1[2] * s1)) | (((uint32_t)f2bf(o1[3] * s1)) << 16));
    *(uint2*)(aggS + (size_t)n * 512 + (p * 2) * 128 + c0) = w0;
    *(uint2*)(aggS + (size_t)n * 512 + (p * 2 + 1) * 128 + c0) = w1;
  }
}

// ---------------- agg GEMM: attn = aggS(bf16, Nx512) @ WeB^T(bf16, 128x512) + wsS ----------------
__launch_bounds__(256)
__global__ void agg_gemm_kernel(const ushort* __restrict__ aggS, const ushort* __restrict__ WeB,
                                const float* __restrict__ wsX, float* __restrict__ attn, int N)
{
  __shared__ ushort As[128][72];
  __shared__ ushort Bs[128][72];
  const int tid = threadIdx.x;
  const int nb = blockIdx.x * 128;
  const int lane = tid & 63, wv = tid >> 6;
  const int wr = (wv >> 1) * 64, wc = (wv & 1) * 64;
  const int fr = lane & 15, fq = lane >> 4;
  const int r = tid >> 1, cs = (tid & 1) * 32;

  f32x4 acc[4][4];
#pragma unroll
  for (int m = 0; m < 4; ++m)
#pragma unroll
    for (int n = 0; n < 4; ++n) acc[m][n] = (f32x4)0.0f;

  for (int kc = 0; kc < 512; kc += 64) {
    uint4 av[4], bv[4];
    if (nb + r < N) {
      const uint4* src = (const uint4*)(aggS + (size_t)(nb + r) * 512 + kc + cs);
      av[0] = src[0]; av[1] = src[1]; av[2] = src[2]; av[3] = src[3];
    } else {
#pragma unroll
      for (int i = 0; i < 4; ++i) av[i] = make_uint4(0, 0, 0, 0);
    }
    {
      const uint4* src = (const uint4*)(WeB + (size_t)r * 512 + kc + cs);
      bv[0] = src[0]; bv[1] = src[1]; bv[2] = src[2]; bv[3] = src[3];
    }
    if (kc) __syncthreads();
#pragma unroll
    for (int i = 0; i < 4; ++i) {
      *(uint4*)&As[r][cs + i * 8] = av[i];
      *(uint4*)&Bs[r][cs + i * 8] = bv[i];
    }
    __syncthreads();

#pragma unroll
    for (int s = 0; s < 2; ++s) {
      bf16x8 ah[4], bh[4];
#pragma unroll
      for (int m = 0; m < 4; ++m)
        ah[m] = *(const bf16x8*)&As[wr + m * 16 + fr][s * 32 + fq * 8];
#pragma unroll
      for (int n = 0; n < 4; ++n)
        bh[n] = *(const bf16x8*)&Bs[wc + n * 16 + fr][s * 32 + fq * 8];
#pragma unroll
      for (int m = 0; m < 4; ++m)
#pragma unroll
        for (int n = 0; n < 4; ++n)
          acc[m][n] = __builtin_amdgcn_mfma_f32_16x16x32_bf16(ah[m], bh[n], acc[m][n], 0, 0, 0);
    }
  }

#pragma unroll
  for (int m = 0; m < 4; ++m) {
    const int r0 = nb + wr + m * 16 + fq * 4;
#pragma unroll
    for (int rr = 0; rr < 4; ++rr) {
      const int gr = r0 + rr;
      if (gr < N) {
#pragma unroll
        for (int n = 0; n < 4; ++n) {
          const int c = wc + n * 16 + fr;
          attn[(size_t)gr * 128 + c] = acc[m][n][rr] + wsX[(size_t)gr * 128 + c];
        }
      }
    }
  }
}

// ---------------- column LayerNorm stats over node dim ----------------
__launch_bounds__(256)
__global__ void stats_kernel(const float* __restrict__ t1, float* __restrict__ sums,
                             float* __restrict__ sumsq, int N)
{
  const int tid = threadIdx.x;
  const int c = tid & 127, half = tid >> 7;
  float s = 0.f, s2 = 0.f;
  for (int r = blockIdx.x * 2 + half; r < N; r += gridDim.x * 2) {
    float vv = t1[(size_t)r * 128 + c];
    s += vv; s2 = fmaf(vv, vv, s2);
  }
  __shared__ float ls[256], ls2[256];
  ls[tid] = s; ls2[tid] = s2;
  __syncthreads();
  if (tid < 128) {
    atomicAdd(&sums[c], ls[tid] + ls[tid + 128]);
    atomicAdd(&sumsq[c], ls2[tid] + ls2[tid + 128]);
  }
}

__global__ void finalize_stats_kernel(const float* __restrict__ sums, const float* __restrict__ sumsq,
                                      float* __restrict__ mu, float* __restrict__ inv, int N)
{
  int c = threadIdx.x;
  float m = sums[c] / (float)N;
  float var = sumsq[c] / (float)N - m * m;
  float sd = sqrtf(fmaxf(var, 0.f));
  mu[c] = m;
  inv[c] = 1.f / (sd + 1e-5f);
}

extern "C" void kernel_launch(void* const* d_in, const int* in_sizes, int n_in,
                              void* d_out, int out_size, void* d_ws, size_t ws_size,
                              hipStream_t stream) {
  const float* x    = (const float*)d_in[0];
  const int*   ei   = (const int*)d_in[1];
  const float* eatt = (const float*)d_in[2];
  const float* Wq = (const float*)d_in[3];  const float* bq = (const float*)d_in[4];
  const float* Wk = (const float*)d_in[5];  const float* bk = (const float*)d_in[6];
  const float* Wv = (const float*)d_in[7];  const float* bv = (const float*)d_in[8];
  const float* We = (const float*)d_in[9];
  const float* Wsk = (const float*)d_in[10]; const float* bsk = (const float*)d_in[11];
  const float* Wp = (const float*)d_in[12]; const float* bp = (const float*)d_in[13];
  const float* Wm = (const float*)d_in[14]; const float* bm = (const float*)d_in[15];
  float* out = (float*)d_out;

  const int N = in_sizes[0] / 128;
  const int E = in_sizes[1] / 2;

  char* w = (char*)d_ws;
  auto alloc = [&](size_t bytes) {
    char* p = w;
    w += (bytes + 255) & ~(size_t)255;
    return p;
  };
  const size_t node_f = (size_t)N * 128 * sizeof(float);
  float*  q    = (float*)alloc(node_f);
  float*  kk   = (float*)alloc(node_f);
  float*  vv   = (float*)alloc(node_f);
  float*  skip = (float*)alloc(node_f);
  float*  wsA  = (float*)alloc(node_f);                       // wsS, then attn (aliased)
  ushort* u    = (ushort*)alloc((size_t)N * 512 * sizeof(ushort));
  ushort* aggS = (ushort*)alloc((size_t)N * 512 * sizeof(ushort));
  ushort* WeB  = (ushort*)alloc(128 * 512 * sizeof(ushort));
  int*    deg  = (int*)alloc((size_t)N * sizeof(int));
  int*    offs = (int*)alloc((size_t)N * sizeof(int));
  int*    curs = (int*)alloc((size_t)N * sizeof(int));
  int*    gcnt = (int*)alloc(sizeof(int));
  int2*   csr  = (int2*)alloc((size_t)E * sizeof(int2));
  float*  sums  = (float*)alloc(128 * sizeof(float));
  float*  sumsq = (float*)alloc(128 * sizeof(float));
  float*  mu    = (float*)alloc(128 * sizeof(float));
  float*  inv   = (float*)alloc(128 * sizeof(float));
  float*  t1   = q;   // q dead after fused_attn2; reuse
  (void)ws_size; (void)n_in; (void)out_size;

  const int NB = (N + 127) / 128;
  const int EB = (E + 255) / 256;

  hipMemsetAsync(deg, 0, (size_t)N * sizeof(int), stream);
  hipMemsetAsync(gcnt, 0, sizeof(int), stream);
  hipMemsetAsync(sums, 0, 2 * 128 * sizeof(float), stream);  // sums + sumsq contiguous

  // node projections: q,k,v,skip (MFMA bf16x3)
  gemmqkvs_mfma_kernel<<<dim3(NB, 4), 256, 0, stream>>>(x, Wq, bq, Wk, bk, Wv, bv, Wsk, bsk,
                                                        q, kk, vv, skip, N);
  u_kernel<<<(N + 63) / 64, 256, 0, stream>>>(q, We, u, N);
  prep_web_kernel<<<256, 256, 0, stream>>>(We, WeB);

  // CSR by dst
  deg_kernel<<<EB, 256, 0, stream>>>(ei, deg, E);
  start_kernel<<<(N + 255) / 256, 256, 0, stream>>>(deg, offs, curs, gcnt, N);
  fill_kernel<<<EB, 256, 0, stream>>>(ei, curs, csr, E);

  // fused attention: scores + softmax + aggregation (pipelined gathers, no LDS)
  fused_attn2_kernel<<<2048, 256, 0, stream>>>(csr, offs, deg, q, kk, vv, u, eatt,
                                               aggS, wsA, N);

  // attn = aggS @ WeB^T + wsS  (MFMA; writes in place over wsA)
  agg_gemm_kernel<<<NB, 256, 0, stream>>>(aggS, WeB, wsA, wsA, N);

  // t1 = relu(attn + skip) @ Wp^T + bp  (MFMA bf16x3)
  gemm128_mfma_kernel<<<NB, 256, 0, stream>>>(1, wsA, skip, Wp, bp, nullptr, nullptr, nullptr, t1, N);

  // column LayerNorm over node dim
  stats_kernel<<<256, 256, 0, stream>>>(t1, sums, sumsq, N);
  finalize_stats_kernel<<<1, 128, 0, stream>>>(sums, sumsq, mu, inv, N);

  // out = relu((t1 - mu) * inv) @ Wm^T + bm + x  (MFMA bf16x3)
  gemm128_mfma_kernel<<<NB, 256, 0, stream>>>(2, t1, nullptr, Wm, bm, mu, inv, x, out, N);
}

// Round 6
// 512.493 us; speedup vs baseline: 1.2859x; 1.0910x over previous
//
#include <hip/hip_runtime.h>
#include <stdint.h>

#define RS32 0.17677669529663687f  // 1/sqrt(32)
#define LDW 40                     // ushort stride per LDS row (32 + 8 pad; 80B, 16B-aligned)

typedef short bf16x8 __attribute__((ext_vector_type(8)));
typedef float f32x4 __attribute__((ext_vector_type(4)));

__device__ __forceinline__ ushort f2bf(float f) {
  uint32_t b = __float_as_uint(f);
  b = (b + 0x7fffu + ((b >> 16) & 1u)) >> 16;
  return (ushort)b;
}
__device__ __forceinline__ float bflo(uint32_t w) { return __uint_as_float(w << 16); }
__device__ __forceinline__ float bfhi(uint32_t w) { return __uint_as_float(w & 0xffff0000u); }

// split 16 fp32 into hi/lo bf16 and store to LDS row r at koff (both 16B-aligned stores)
__device__ __forceinline__ void stage16(ushort* hiA, ushort* loA, int r, int koff,
                                        const float* v) {
  uint32_t hu[8], lu[8];
#pragma unroll
  for (int i = 0; i < 8; ++i) {
    ushort h0 = f2bf(v[2 * i]), h1 = f2bf(v[2 * i + 1]);
    float f0 = __uint_as_float(((uint32_t)h0) << 16);
    float f1 = __uint_as_float(((uint32_t)h1) << 16);
    ushort l0 = f2bf(v[2 * i] - f0), l1 = f2bf(v[2 * i + 1] - f1);
    hu[i] = (uint32_t)h0 | ((uint32_t)h1 << 16);
    lu[i] = (uint32_t)l0 | ((uint32_t)l1 << 16);
  }
  *(uint4*)&hiA[r * LDW + koff]     = make_uint4(hu[0], hu[1], hu[2], hu[3]);
  *(uint4*)&hiA[r * LDW + koff + 8] = make_uint4(hu[4], hu[5], hu[6], hu[7]);
  *(uint4*)&loA[r * LDW + koff]     = make_uint4(lu[0], lu[1], lu[2], lu[3]);
  *(uint4*)&loA[r * LDW + koff + 8] = make_uint4(lu[4], lu[5], lu[6], lu[7]);
}

// ---------------- MFMA bf16x3 GEMM: out = ep(g(A) @ W^T), N x 128, K=128 ----------------
// mode 1: g=relu(A+A2), ep=+bias, + fused column-stats (sums/sumsq atomics).
// mode 2: g=relu((A-mu)*inv), ep=+bias+X.
__launch_bounds__(256)
__global__ void gemm128_mfma_kernel(int mode,
                                    const float* __restrict__ A, const float* __restrict__ A2,
                                    const float* __restrict__ W, const float* __restrict__ bias,
                                    const float* __restrict__ mu, const float* __restrict__ inv,
                                    const float* __restrict__ X, float* __restrict__ out,
                                    float* __restrict__ sums, float* __restrict__ sumsq, int N)
{
  __shared__ ushort Ahi[128 * LDW], Alo[128 * LDW], Whi[128 * LDW], Wlo[128 * LDW];
  const int tid = threadIdx.x;
  const int nb = blockIdx.x * 128;
  const int lane = tid & 63, wv = tid >> 6;
  const int wr = (wv >> 1) * 64, wc = (wv & 1) * 64;
  const int fr = lane & 15, fq = lane >> 4;
  const int sr = tid >> 1, sk = (tid & 1) * 16;

  f32x4 acc[4][4];
#pragma unroll
  for (int m = 0; m < 4; ++m)
#pragma unroll
    for (int n = 0; n < 4; ++n) acc[m][n] = (f32x4)0.0f;

  for (int kc = 0; kc < 128; kc += 32) {
    float va[16], vw[16];
    {
      int gr = nb + sr;
      if (gr < N) {
#pragma unroll
        for (int i = 0; i < 4; ++i) {
          float4 v = *(const float4*)(A + (size_t)gr * 128 + kc + sk + i * 4);
          if (mode == 1) {
            float4 b = *(const float4*)(A2 + (size_t)gr * 128 + kc + sk + i * 4);
            v.x = fmaxf(v.x + b.x, 0.f); v.y = fmaxf(v.y + b.y, 0.f);
            v.z = fmaxf(v.z + b.z, 0.f); v.w = fmaxf(v.w + b.w, 0.f);
          } else if (mode == 2) {
            float4 m4 = *(const float4*)(mu + kc + sk + i * 4);
            float4 i4 = *(const float4*)(inv + kc + sk + i * 4);
            v.x = fmaxf((v.x - m4.x) * i4.x, 0.f); v.y = fmaxf((v.y - m4.y) * i4.y, 0.f);
            v.z = fmaxf((v.z - m4.z) * i4.z, 0.f); v.w = fmaxf((v.w - m4.w) * i4.w, 0.f);
          }
          va[i * 4 + 0] = v.x; va[i * 4 + 1] = v.y; va[i * 4 + 2] = v.z; va[i * 4 + 3] = v.w;
        }
      } else {
#pragma unroll
        for (int i = 0; i < 16; ++i) va[i] = 0.f;
      }
#pragma unroll
      for (int i = 0; i < 4; ++i) {
        float4 v = *(const float4*)(W + (size_t)sr * 128 + kc + sk + i * 4);
        vw[i * 4 + 0] = v.x; vw[i * 4 + 1] = v.y; vw[i * 4 + 2] = v.z; vw[i * 4 + 3] = v.w;
      }
    }
    if (kc) __syncthreads();
    stage16(Ahi, Alo, sr, sk, va);
    stage16(Whi, Wlo, sr, sk, vw);
    __syncthreads();

    bf16x8 ah[4], al[4], bh[4], bl[4];
#pragma unroll
    for (int m = 0; m < 4; ++m) {
      const int row = wr + m * 16 + fr;
      ah[m] = *(const bf16x8*)&Ahi[row * LDW + fq * 8];
      al[m] = *(const bf16x8*)&Alo[row * LDW + fq * 8];
    }
#pragma unroll
    for (int n = 0; n < 4; ++n) {
      const int col = wc + n * 16 + fr;
      bh[n] = *(const bf16x8*)&Whi[col * LDW + fq * 8];
      bl[n] = *(const bf16x8*)&Wlo[col * LDW + fq * 8];
    }
#pragma unroll
    for (int m = 0; m < 4; ++m)
#pragma unroll
      for (int n = 0; n < 4; ++n) {
        acc[m][n] = __builtin_amdgcn_mfma_f32_16x16x32_bf16(ah[m], bh[n], acc[m][n], 0, 0, 0);
        acc[m][n] = __builtin_amdgcn_mfma_f32_16x16x32_bf16(al[m], bh[n], acc[m][n], 0, 0, 0);
        acc[m][n] = __builtin_amdgcn_mfma_f32_16x16x32_bf16(ah[m], bl[n], acc[m][n], 0, 0, 0);
      }
  }

  float bcol[4];
#pragma unroll
  for (int n = 0; n < 4; ++n) bcol[n] = bias[wc + n * 16 + fr];
  float csum[4] = {0.f, 0.f, 0.f, 0.f}, csum2[4] = {0.f, 0.f, 0.f, 0.f};
#pragma unroll
  for (int m = 0; m < 4; ++m) {
    const int r0 = nb + wr + m * 16 + fq * 4;
#pragma unroll
    for (int r = 0; r < 4; ++r) {
      const int gr = r0 + r;
      if (gr < N) {
#pragma unroll
        for (int n = 0; n < 4; ++n) {
          const int c = wc + n * 16 + fr;
          float o = acc[m][n][r] + bcol[n];
          if (mode == 2) o += X[(size_t)gr * 128 + c];
          out[(size_t)gr * 128 + c] = o;
          if (mode == 1) { csum[n] += o; csum2[n] = fmaf(o, o, csum2[n]); }
        }
      }
    }
  }
  if (mode == 1) {
#pragma unroll
    for (int n = 0; n < 4; ++n) {
      csum[n] += __shfl_xor(csum[n], 16, 64);
      csum[n] += __shfl_xor(csum[n], 32, 64);
      csum2[n] += __shfl_xor(csum2[n], 16, 64);
      csum2[n] += __shfl_xor(csum2[n], 32, 64);
    }
    if (fq == 0) {
#pragma unroll
      for (int n = 0; n < 4; ++n) {
        atomicAdd(&sums[wc + n * 16 + fr], csum[n]);
        atomicAdd(&sumsq[wc + n * 16 + fr], csum2[n]);
      }
    }
  }
}

// ---------------- MFMA QKVS: y=0 -> q(fp32), y=1 -> kvb k-half(bf16), y=2 -> kvb v-half,
// y=3 -> skip(fp32) ----------------
__launch_bounds__(256)
__global__ void gemmqkvs_mfma_kernel(const float* __restrict__ x,
                                     const float* __restrict__ Wq, const float* __restrict__ bq,
                                     const float* __restrict__ Wk, const float* __restrict__ bk,
                                     const float* __restrict__ Wv, const float* __restrict__ bv,
                                     const float* __restrict__ Ws, const float* __restrict__ bs,
                                     float* __restrict__ oq, float* __restrict__ os,
                                     ushort* __restrict__ kvb, int N)
{
  const float* W; const float* bias;
  if (blockIdx.y == 0)      { W = Wq; bias = bq; }
  else if (blockIdx.y == 1) { W = Wk; bias = bk; }
  else if (blockIdx.y == 2) { W = Wv; bias = bv; }
  else                      { W = Ws; bias = bs; }

  __shared__ ushort Ahi[128 * LDW], Alo[128 * LDW], Whi[128 * LDW], Wlo[128 * LDW];
  const int tid = threadIdx.x;
  const int nb = blockIdx.x * 128;
  const int lane = tid & 63, wv = tid >> 6;
  const int wr = (wv >> 1) * 64, wc = (wv & 1) * 64;
  const int fr = lane & 15, fq = lane >> 4;
  const int sr = tid >> 1, sk = (tid & 1) * 16;

  f32x4 acc[4][4];
#pragma unroll
  for (int m = 0; m < 4; ++m)
#pragma unroll
    for (int n = 0; n < 4; ++n) acc[m][n] = (f32x4)0.0f;

  for (int kc = 0; kc < 128; kc += 32) {
    float va[16], vw[16];
    {
      int gr = nb + sr;
      if (gr < N) {
#pragma unroll
        for (int i = 0; i < 4; ++i) {
          float4 v = *(const float4*)(x + (size_t)gr * 128 + kc + sk + i * 4);
          va[i * 4 + 0] = v.x; va[i * 4 + 1] = v.y; va[i * 4 + 2] = v.z; va[i * 4 + 3] = v.w;
        }
      } else {
#pragma unroll
        for (int i = 0; i < 16; ++i) va[i] = 0.f;
      }
#pragma unroll
      for (int i = 0; i < 4; ++i) {
        float4 v = *(const float4*)(W + (size_t)sr * 128 + kc + sk + i * 4);
        vw[i * 4 + 0] = v.x; vw[i * 4 + 1] = v.y; vw[i * 4 + 2] = v.z; vw[i * 4 + 3] = v.w;
      }
    }
    if (kc) __syncthreads();
    stage16(Ahi, Alo, sr, sk, va);
    stage16(Whi, Wlo, sr, sk, vw);
    __syncthreads();

    bf16x8 ah[4], al[4], bh[4], bl[4];
#pragma unroll
    for (int m = 0; m < 4; ++m) {
      const int row = wr + m * 16 + fr;
      ah[m] = *(const bf16x8*)&Ahi[row * LDW + fq * 8];
      al[m] = *(const bf16x8*)&Alo[row * LDW + fq * 8];
    }
#pragma unroll
    for (int n = 0; n < 4; ++n) {
      const int col = wc + n * 16 + fr;
      bh[n] = *(const bf16x8*)&Whi[col * LDW + fq * 8];
      bl[n] = *(const bf16x8*)&Wlo[col * LDW + fq * 8];
    }
#pragma unroll
    for (int m = 0; m < 4; ++m)
#pragma unroll
      for (int n = 0; n < 4; ++n) {
        acc[m][n] = __builtin_amdgcn_mfma_f32_16x16x32_bf16(ah[m], bh[n], acc[m][n], 0, 0, 0);
        acc[m][n] = __builtin_amdgcn_mfma_f32_16x16x32_bf16(al[m], bh[n], acc[m][n], 0, 0, 0);
        acc[m][n] = __builtin_amdgcn_mfma_f32_16x16x32_bf16(ah[m], bl[n], acc[m][n], 0, 0, 0);
      }
  }

  float bcol[4];
#pragma unroll
  for (int n = 0; n < 4; ++n) bcol[n] = bias[wc + n * 16 + fr];
  const int y = blockIdx.y;
  float* outf = (y == 0) ? oq : os;
  const int voff = (y == 2) ? 128 : 0;
#pragma unroll
  for (int m = 0; m < 4; ++m) {
    const int r0 = nb + wr + m * 16 + fq * 4;
#pragma unroll
    for (int r = 0; r < 4; ++r) {
      const int gr = r0 + r;
      if (gr < N) {
#pragma unroll
        for (int n = 0; n < 4; ++n) {
          const int c = wc + n * 16 + fr;
          float o = acc[m][n][r] + bcol[n];
          if (y == 0 || y == 3) outf[(size_t)gr * 128 + c] = o;
          else kvb[(size_t)gr * 256 + voff + c] = f2bf(o);
        }
      }
    }
  }
}

// ---------------- u[n, h*128+j] = sum_{c<32} q[n, 32h+c] * We[32h+c, j]  (bf16 out) ----------------
__launch_bounds__(256)
__global__ void u_kernel(const float* __restrict__ q, const float* __restrict__ We,
                         ushort* __restrict__ u, int N)
{
  __shared__ float qs[64][128];
  const int tid = threadIdx.x;
  const int nb = blockIdx.x * 64;
  for (int idx = tid; idx < 64 * 128; idx += 256) {
    int r = idx >> 7, kk = idx & 127;
    qs[r][kk] = (nb + r < N) ? q[(size_t)(nb + r) * 128 + kk] : 0.f;
  }
  __syncthreads();
  const int j = tid & 127, half = tid >> 7;
  for (int h = 0; h < 4; ++h) {
    float w[32];
#pragma unroll
    for (int c = 0; c < 32; ++c) w[c] = We[(size_t)(32 * h + c) * 128 + j];
    for (int nn = half; nn < 64; nn += 2) {
      float acc = 0.f;
#pragma unroll
      for (int c4 = 0; c4 < 32; c4 += 4) {
        float4 qq = *(const float4*)&qs[nn][32 * h + c4];
        acc = fmaf(qq.x, w[c4], acc);
        acc = fmaf(qq.y, w[c4 + 1], acc);
        acc = fmaf(qq.z, w[c4 + 2], acc);
        acc = fmaf(qq.w, w[c4 + 3], acc);
      }
      int gr = nb + nn;
      if (gr < N) u[(size_t)gr * 512 + h * 128 + j] = f2bf(acc);
    }
  }
}

// ---------------- WeB[c][h*128+k] = (h == c>>5) ? bf16(We[c,k]) : 0  (block-diag, 128x512) ----
__global__ void prep_web_kernel(const float* __restrict__ We, ushort* __restrict__ WeB)
{
  int idx = blockIdx.x * 256 + threadIdx.x;
  if (idx >= 128 * 512) return;
  int c = idx >> 9, j = idx & 511;
  int hh = j >> 7, k2 = j & 127;
  WeB[idx] = (hh == (c >> 5)) ? f2bf(We[(size_t)c * 128 + k2]) : (ushort)0;
}

// ---------------- CSR build ----------------
__global__ void deg_kernel(const int* __restrict__ ei, int* __restrict__ deg, int E)
{
  int e = blockIdx.x * 256 + threadIdx.x;
  if (e < E) atomicAdd(&deg[ei[E + e]], 1);
}

__launch_bounds__(256)
__global__ void start_kernel(const int* __restrict__ deg, int* __restrict__ offs,
                             int* __restrict__ cursor, int* __restrict__ gcount, int N)
{
  const int i = blockIdx.x * 256 + threadIdx.x;
  const int lane = threadIdx.x & 63;
  int d = (i < N) ? deg[i] : 0;
  int scan = d;
#pragma unroll
  for (int ofs = 1; ofs < 64; ofs <<= 1) {
    int t = __shfl_up(scan, ofs, 64);
    if (lane >= ofs) scan += t;
  }
  int total = __shfl(scan, 63, 64);
  int base = 0;
  if (lane == 63) base = atomicAdd(gcount, total);
  base = __shfl(base, 63, 64);
  int excl = base + scan - d;
  if (i < N) { offs[i] = excl; cursor[i] = excl; }
}

__global__ void fill_kernel(const int* __restrict__ ei, int* __restrict__ cursor,
                            int2* __restrict__ csr, int E)
{
  int e = blockIdx.x * 256 + threadIdx.x;
  if (e < E) {
    int dst = ei[E + e];
    int slot = atomicAdd(&cursor[dst], 1);
    csr[slot] = make_int2(ei[e], e);
  }
}

// ---------------- fused node-major attention: score + softmax + aggregate ----------------
// wave per node; 2 edge slots of 32 lanes; lane (p, j32) owns channels 4*j32..+3 (head j32>>3).
// k/v gathered as packed bf16 from kvb[n][256]. Outputs: aggS bf16, wsS fp32.
__launch_bounds__(256)
__global__ void fused_attn2_kernel(const int2* __restrict__ csr, const int* __restrict__ offs,
                                   const int* __restrict__ deg,
                                   const float* __restrict__ q, const ushort* __restrict__ kvb,
                                   const ushort* __restrict__ u,
                                   const float* __restrict__ eattr,
                                   ushort* __restrict__ aggS, float* __restrict__ wsS, int N)
{
  const int tid = threadIdx.x;
  const int lane = tid & 63;
  const int wid = tid >> 6;
  const int p = lane >> 5;          // edge slot 0/1
  const int j32 = lane & 31;
  const int c0 = j32 * 4;           // my 4 channels
  const int h = j32 >> 3;           // head of my channels
  const int gwave = blockIdx.x * 4 + wid;
  const int nwaves = gridDim.x * 4;

  for (int n = gwave; n < N; n += nwaves) {
    const int e0 = offs[n];
    const int e1 = e0 + deg[n];

    const float4 qv = *(const float4*)(q + (size_t)n * 128 + c0);
    float uh[4][4];
#pragma unroll
    for (int hh = 0; hh < 4; ++hh) {
      uint2 U = *(const uint2*)(u + (size_t)n * 512 + hh * 128 + c0);
      uh[hh][0] = bflo(U.x); uh[hh][1] = bfhi(U.x);
      uh[hh][2] = bflo(U.y); uh[hh][3] = bfhi(U.y);
    }

    float ws0 = 0.f, ws1 = 0.f, ws2 = 0.f, ws3 = 0.f;
    float ax[4][4];
#pragma unroll
    for (int hh = 0; hh < 4; ++hh)
#pragma unroll
      for (int j = 0; j < 4; ++j) ax[hh][j] = 0.f;
    float sm0 = 0.f, sm1 = 0.f, sm2 = 0.f, sm3 = 0.f;

    int sl = e0 + p;
    if (sl < e1) {
      int2 seC = csr[sl];
      float4 eaC = *(const float4*)(eattr + (size_t)seC.y * 128 + c0);
      uint2 kC = *(const uint2*)(kvb + (size_t)seC.x * 256 + c0);
      uint2 vC = *(const uint2*)(kvb + (size_t)seC.x * 256 + 128 + c0);
      int sln = sl + 2;
      int2 seN = (sln < e1) ? csr[sln] : seC;
      for (; sl < e1; sl += 2) {
        // prefetch next edge's rows + csr two ahead
        float4 eaN = *(const float4*)(eattr + (size_t)seN.y * 128 + c0);
        uint2 kN = *(const uint2*)(kvb + (size_t)seN.x * 256 + c0);
        uint2 vN = *(const uint2*)(kvb + (size_t)seN.x * 256 + 128 + c0);
        const int slf = sl + 4;
        int2 seF = (slf < e1) ? csr[slf] : seN;

        const float kf0 = bflo(kC.x), kf1 = bfhi(kC.x), kf2 = bflo(kC.y), kf3 = bfhi(kC.y);
        const float vf0 = bflo(vC.x), vf1 = bfhi(vC.x), vf2 = bflo(vC.y), vf3 = bfhi(vC.y);

        // scores for current edge
        float P0 = eaC.x * uh[0][0] + eaC.y * uh[0][1] + eaC.z * uh[0][2] + eaC.w * uh[0][3];
        float P1 = eaC.x * uh[1][0] + eaC.y * uh[1][1] + eaC.z * uh[1][2] + eaC.w * uh[1][3];
        float P2 = eaC.x * uh[2][0] + eaC.y * uh[2][1] + eaC.z * uh[2][2] + eaC.w * uh[2][3];
        float P3 = eaC.x * uh[3][0] + eaC.y * uh[3][1] + eaC.z * uh[3][2] + eaC.w * uh[3][3];
        const float qk = qv.x * kf0 + qv.y * kf1 + qv.z * kf2 + qv.w * kf3;
        P0 += (h == 0) ? qk : 0.f;
        P1 += (h == 1) ? qk : 0.f;
        P2 += (h == 2) ? qk : 0.f;
        P3 += (h == 3) ? qk : 0.f;
#pragma unroll
        for (int mm = 1; mm <= 16; mm <<= 1) {
          P0 += __shfl_xor(P0, mm, 64);
          P1 += __shfl_xor(P1, mm, 64);
          P2 += __shfl_xor(P2, mm, 64);
          P3 += __shfl_xor(P3, mm, 64);
        }
        const float a0 = __expf(P0 * RS32);
        const float a1 = __expf(P1 * RS32);
        const float a2 = __expf(P2 * RS32);
        const float a3 = __expf(P3 * RS32);
        sm0 += a0; sm1 += a1; sm2 += a2; sm3 += a3;
        const float aV = (h == 0) ? a0 : (h == 1) ? a1 : (h == 2) ? a2 : a3;
        ws0 = fmaf(aV, vf0, ws0); ws1 = fmaf(aV, vf1, ws1);
        ws2 = fmaf(aV, vf2, ws2); ws3 = fmaf(aV, vf3, ws3);
        ax[0][0] = fmaf(a0, eaC.x, ax[0][0]); ax[0][1] = fmaf(a0, eaC.y, ax[0][1]);
        ax[0][2] = fmaf(a0, eaC.z, ax[0][2]); ax[0][3] = fmaf(a0, eaC.w, ax[0][3]);
        ax[1][0] = fmaf(a1, eaC.x, ax[1][0]); ax[1][1] = fmaf(a1, eaC.y, ax[1][1]);
        ax[1][2] = fmaf(a1, eaC.z, ax[1][2]); ax[1][3] = fmaf(a1, eaC.w, ax[1][3]);
        ax[2][0] = fmaf(a2, eaC.x, ax[2][0]); ax[2][1] = fmaf(a2, eaC.y, ax[2][1]);
        ax[2][2] = fmaf(a2, eaC.z, ax[2][2]); ax[2][3] = fmaf(a2, eaC.w, ax[2][3]);
        ax[3][0] = fmaf(a3, eaC.x, ax[3][0]); ax[3][1] = fmaf(a3, eaC.y, ax[3][1]);
        ax[3][2] = fmaf(a3, eaC.z, ax[3][2]); ax[3][3] = fmaf(a3, eaC.w, ax[3][3]);

        eaC = eaN; kC = kN; vC = vN; seN = seF;
      }
    }

    // combine the two edge slots (xor 32)
#pragma unroll
    for (int hh = 0; hh < 4; ++hh)
#pragma unroll
      for (int j = 0; j < 4; ++j) ax[hh][j] += __shfl_xor(ax[hh][j], 32, 64);
    ws0 += __shfl_xor(ws0, 32, 64); ws1 += __shfl_xor(ws1, 32, 64);
    ws2 += __shfl_xor(ws2, 32, 64); ws3 += __shfl_xor(ws3, 32, 64);
    sm0 += __shfl_xor(sm0, 32, 64); sm1 += __shfl_xor(sm1, 32, 64);
    sm2 += __shfl_xor(sm2, 32, 64); sm3 += __shfl_xor(sm3, 32, 64);

    const float iv0 = (sm0 > 0.f) ? 1.f / sm0 : 0.f;
    const float iv1 = (sm1 > 0.f) ? 1.f / sm1 : 0.f;
    const float iv2 = (sm2 > 0.f) ? 1.f / sm2 : 0.f;
    const float iv3 = (sm3 > 0.f) ? 1.f / sm3 : 0.f;

    if (p == 0) {
      const float s = (h == 0) ? iv0 : (h == 1) ? iv1 : (h == 2) ? iv2 : iv3;
      *(float4*)(wsS + (size_t)n * 128 + c0) =
          make_float4(ws0 * s, ws1 * s, ws2 * s, ws3 * s);
    }

    // lane writes heads {2p, 2p+1} for its channel quad
    float o0[4], o1[4], s0, s1;
    if (p == 0) {
#pragma unroll
      for (int j = 0; j < 4; ++j) { o0[j] = ax[0][j]; o1[j] = ax[1][j]; }
      s0 = iv0; s1 = iv1;
    } else {
#pragma unroll
      for (int j = 0; j < 4; ++j) { o0[j] = ax[2][j]; o1[j] = ax[3][j]; }
      s0 = iv2; s1 = iv3;
    }
    uint2 w0 = make_uint2(((uint32_t)f2bf(o0[0] * s0)) | (((uint32_t)f2bf(o0[1] * s0)) << 16),
                          ((uint32_t)f2bf(o0[2] * s0)) | (((uint32_t)f2bf(o0[3] * s0)) << 16));
    uint2 w1 = make_uint2(((uint32_t)f2bf(o1[0] * s1)) | (((uint32_t)f2bf(o1[1] * s1)) << 16),
                          ((uint32_t)f2bf(o1[2] * s1)) | (((uint32_t)f2bf(o1[3] * s1)) << 16));
    *(uint2*)(aggS + (size_t)n * 512 + (p * 2) * 128 + c0) = w0;
    *(uint2*)(aggS + (size_t)n * 512 + (p * 2 + 1) * 128 + c0) = w1;
  }
}

// ---------------- agg GEMM: attn = aggS(bf16, Nx512) @ WeB^T(bf16, 128x512) + wsS ----------------
__launch_bounds__(256)
__global__ void agg_gemm_kernel(const ushort* __restrict__ aggS, const ushort* __restrict__ WeB,
                                const float* __restrict__ wsX, float* __restrict__ attn, int N)
{
  __shared__ ushort As[128][72];
  __shared__ ushort Bs[128][72];
  const int tid = threadIdx.x;
  const int nb = blockIdx.x * 128;
  const int lane = tid & 63, wv = tid >> 6;
  const int wr = (wv >> 1) * 64, wc = (wv & 1) * 64;
  const int fr = lane & 15, fq = lane >> 4;
  const int r = tid >> 1, cs = (tid & 1) * 32;

  f32x4 acc[4][4];
#pragma unroll
  for (int m = 0; m < 4; ++m)
#pragma unroll
    for (int n = 0; n < 4; ++n) acc[m][n] = (f32x4)0.0f;

  for (int kc = 0; kc < 512; kc += 64) {
    uint4 av[4], bv[4];
    if (nb + r < N) {
      const uint4* src = (const uint4*)(aggS + (size_t)(nb + r) * 512 + kc + cs);
      av[0] = src[0]; av[1] = src[1]; av[2] = src[2]; av[3] = src[3];
    } else {
#pragma unroll
      for (int i = 0; i < 4; ++i) av[i] = make_uint4(0, 0, 0, 0);
    }
    {
      const uint4* src = (const uint4*)(WeB + (size_t)r * 512 + kc + cs);
      bv[0] = src[0]; bv[1] = src[1]; bv[2] = src[2]; bv[3] = src[3];
    }
    if (kc) __syncthreads();
#pragma unroll
    for (int i = 0; i < 4; ++i) {
      *(uint4*)&As[r][cs + i * 8] = av[i];
      *(uint4*)&Bs[r][cs + i * 8] = bv[i];
    }
    __syncthreads();

#pragma unroll
    for (int s = 0; s < 2; ++s) {
      bf16x8 ah[4], bh[4];
#pragma unroll
      for (int m = 0; m < 4; ++m)
        ah[m] = *(const bf16x8*)&As[wr + m * 16 + fr][s * 32 + fq * 8];
#pragma unroll
      for (int n = 0; n < 4; ++n)
        bh[n] = *(const bf16x8*)&Bs[wc + n * 16 + fr][s * 32 + fq * 8];
#pragma unroll
      for (int m = 0; m < 4; ++m)
#pragma unroll
        for (int n = 0; n < 4; ++n)
          acc[m][n] = __builtin_amdgcn_mfma_f32_16x16x32_bf16(ah[m], bh[n], acc[m][n], 0, 0, 0);
    }
  }

#pragma unroll
  for (int m = 0; m < 4; ++m) {
    const int r0 = nb + wr + m * 16 + fq * 4;
#pragma unroll
    for (int rr = 0; rr < 4; ++rr) {
      const int gr = r0 + rr;
      if (gr < N) {
#pragma unroll
        for (int n = 0; n < 4; ++n) {
          const int c = wc + n * 16 + fr;
          attn[(size_t)gr * 128 + c] = acc[m][n][rr] + wsX[(size_t)gr * 128 + c];
        }
      }
    }
  }
}

__global__ void finalize_stats_kernel(const float* __restrict__ sums, const float* __restrict__ sumsq,
                                      float* __restrict__ mu, float* __restrict__ inv, int N)
{
  int c = threadIdx.x;
  float m = sums[c] / (float)N;
  float var = sumsq[c] / (float)N - m * m;
  float sd = sqrtf(fmaxf(var, 0.f));
  mu[c] = m;
  inv[c] = 1.f / (sd + 1e-5f);
}

extern "C" void kernel_launch(void* const* d_in, const int* in_sizes, int n_in,
                              void* d_out, int out_size, void* d_ws, size_t ws_size,
                              hipStream_t stream) {
  const float* x    = (const float*)d_in[0];
  const int*   ei   = (const int*)d_in[1];
  const float* eatt = (const float*)d_in[2];
  const float* Wq = (const float*)d_in[3];  const float* bq = (const float*)d_in[4];
  const float* Wk = (const float*)d_in[5];  const float* bk = (const float*)d_in[6];
  const float* Wv = (const float*)d_in[7];  const float* bv = (const float*)d_in[8];
  const float* We = (const float*)d_in[9];
  const float* Wsk = (const float*)d_in[10]; const float* bsk = (const float*)d_in[11];
  const float* Wp = (const float*)d_in[12]; const float* bp = (const float*)d_in[13];
  const float* Wm = (const float*)d_in[14]; const float* bm = (const float*)d_in[15];
  float* out = (float*)d_out;

  const int N = in_sizes[0] / 128;
  const int E = in_sizes[1] / 2;

  char* w = (char*)d_ws;
  auto alloc = [&](size_t bytes) {
    char* p = w;
    w += (bytes + 255) & ~(size_t)255;
    return p;
  };
  const size_t node_f = (size_t)N * 128 * sizeof(float);
  float*  q    = (float*)alloc(node_f);
  float*  skip = (float*)alloc(node_f);
  float*  wsA  = (float*)alloc(node_f);                        // wsS, then attn (aliased)
  ushort* kvb  = (ushort*)alloc((size_t)N * 256 * sizeof(ushort));
  ushort* u    = (ushort*)alloc((size_t)N * 512 * sizeof(ushort));
  ushort* aggS = (ushort*)alloc((size_t)N * 512 * sizeof(ushort));
  ushort* WeB  = (ushort*)alloc(128 * 512 * sizeof(ushort));
  int*    deg  = (int*)alloc((size_t)N * sizeof(int));
  int*    offs = (int*)alloc((size_t)N * sizeof(int));
  int*    curs = (int*)alloc((size_t)N * sizeof(int));
  int*    gcnt = (int*)alloc(sizeof(int));
  int2*   csr  = (int2*)alloc((size_t)E * sizeof(int2));
  float*  sums  = (float*)alloc(128 * sizeof(float));
  float*  sumsq = (float*)alloc(128 * sizeof(float));
  float*  mu    = (float*)alloc(128 * sizeof(float));
  float*  inv   = (float*)alloc(128 * sizeof(float));
  float*  t1   = q;   // q dead after fused_attn2; reuse
  (void)ws_size; (void)n_in; (void)out_size;

  const int NB = (N + 127) / 128;
  const int EB = (E + 255) / 256;

  hipMemsetAsync(deg, 0, (size_t)N * sizeof(int), stream);
  hipMemsetAsync(gcnt, 0, sizeof(int), stream);
  hipMemsetAsync(sums, 0, 2 * 128 * sizeof(float), stream);  // sums + sumsq contiguous

  // node projections: q fp32, skip fp32, k/v packed bf16 (MFMA bf16x3)
  gemmqkvs_mfma_kernel<<<dim3(NB, 4), 256, 0, stream>>>(x, Wq, bq, Wk, bk, Wv, bv, Wsk, bsk,
                                                        q, skip, kvb, N);
  u_kernel<<<(N + 63) / 64, 256, 0, stream>>>(q, We, u, N);
  prep_web_kernel<<<256, 256, 0, stream>>>(We, WeB);

  // CSR by dst
  deg_kernel<<<EB, 256, 0, stream>>>(ei, deg, E);
  start_kernel<<<(N + 255) / 256, 256, 0, stream>>>(deg, offs, curs, gcnt, N);
  fill_kernel<<<EB, 256, 0, stream>>>(ei, curs, csr, E);

  // fused attention: scores + softmax + aggregation (bf16 packed k/v gathers)
  fused_attn2_kernel<<<2048, 256, 0, stream>>>(csr, offs, deg, q, kvb, u, eatt,
                                               aggS, wsA, N);

  // attn = aggS @ WeB^T + wsS  (MFMA; writes in place over wsA)
  agg_gemm_kernel<<<NB, 256, 0, stream>>>(aggS, WeB, wsA, wsA, N);

  // t1 = relu(attn + skip) @ Wp^T + bp  (MFMA bf16x3) + fused LN column stats
  gemm128_mfma_kernel<<<NB, 256, 0, stream>>>(1, wsA, skip, Wp, bp, nullptr, nullptr, nullptr,
                                              t1, sums, sumsq, N);
  finalize_stats_kernel<<<1, 128, 0, stream>>>(sums, sumsq, mu, inv, N);

  // out = relu((t1 - mu) * inv) @ Wm^T + bm + x  (MFMA bf16x3)
  gemm128_mfma_kernel<<<NB, 256, 0, stream>>>(2, t1, nullptr, Wm, bm, mu, inv, x, out,
                                              nullptr, nullptr, N);
}